// Round 1
// baseline (1749.825 us; speedup 1.0000x reference)
//
#include <hip/hip_runtime.h>

#define NN 100000      // nodes per type (authors == papers == 100000)
#define NE 500000      // edges per relation
#define HD 128         // hidden
#define NBLK 391       // ceil(NN/256)

static __device__ __forceinline__ void fma4(float4& c, float a, const float4 b){
  c.x += a*b.x; c.y += a*b.y; c.z += a*b.z; c.w += a*b.w;
}
static __device__ __forceinline__ void add4(float4& c, const float4 b){
  c.x += b.x; c.y += b.y; c.z += b.z; c.w += b.w;
}

// ============================ CSR build =================================
__global__ void k_count(const int* __restrict__ ei_pa, const int* __restrict__ ei_ap,
                        int* __restrict__ deg2){
  int idx = blockIdx.x * 256 + threadIdx.x;
  if (idx < NE)        atomicAdd(&deg2[      ei_pa[NE + idx]], 1);
  else if (idx < 2*NE) atomicAdd(&deg2[NN + ei_ap[NE + (idx - NE)]], 1);
}

__global__ void k_bsum(const int* __restrict__ deg2, int* __restrict__ bsum){
  int rel = blockIdx.x / NBLK, b = blockIdx.x % NBLK;
  int i = b*256 + threadIdx.x;
  int v = (i < NN) ? deg2[rel*NN + i] : 0;
  __shared__ int s[256];
  s[threadIdx.x] = v; __syncthreads();
  for (int o = 128; o > 0; o >>= 1){
    if (threadIdx.x < o) s[threadIdx.x] += s[threadIdx.x + o];
    __syncthreads();
  }
  if (threadIdx.x == 0) bsum[rel*512 + b] = s[0];
}

__global__ void k_bscan(const int* __restrict__ bsum, int* __restrict__ bsoff){
  int rel = blockIdx.x, t = threadIdx.x;
  int v = (t < NBLK) ? bsum[rel*512 + t] : 0;
  __shared__ int s[512];
  s[t] = v; __syncthreads();
  for (int o = 1; o < 512; o <<= 1){
    int x = (t >= o) ? s[t - o] : 0;
    __syncthreads();
    s[t] += x;
    __syncthreads();
  }
  bsoff[rel*512 + t] = s[t] - v;   // exclusive
}

__global__ void k_scanC(const int* __restrict__ deg2, const int* __restrict__ bsoff,
                        int* __restrict__ off2, int* __restrict__ cur2){
  int rel = blockIdx.x / NBLK, b = blockIdx.x % NBLK;
  int i = b*256 + threadIdx.x, t = threadIdx.x;
  int v = (i < NN) ? deg2[rel*NN + i] : 0;
  __shared__ int s[256];
  s[t] = v; __syncthreads();
  for (int o = 1; o < 256; o <<= 1){
    int x = (t >= o) ? s[t - o] : 0;
    __syncthreads();
    s[t] += x;
    __syncthreads();
  }
  if (i < NN){
    int o = bsoff[rel*512 + b] + s[t] - v;
    off2[rel*NN + i] = o;
    cur2[rel*NN + i] = o;
  }
}

__global__ void k_fill(const int* __restrict__ ei_pa, const int* __restrict__ ei_ap,
                       int* __restrict__ cur2,
                       int* __restrict__ col_pa, int* __restrict__ col_ap){
  int idx = blockIdx.x * 256 + threadIdx.x;
  if (idx < NE){
    int s = ei_pa[idx], d = ei_pa[NE + idx];
    int pos = atomicAdd(&cur2[d], 1);
    col_pa[pos] = s;
  } else if (idx < 2*NE){
    int e = idx - NE;
    int s = ei_ap[e], d = ei_ap[NE + e];
    int pos = atomicAdd(&cur2[NN + d], 1);
    col_ap[pos] = s;
  }
}

// ============================ weight folding ============================
// Wd' = wd @ wu_top, Ws' = ws @ wu_bot  (all K=128, N=128)
struct FoldDesc { const float* A; const float* B; float* C; };
struct FoldArgs { FoldDesc d[8]; int rs[9]; };

__global__ void k_fold(FoldArgs fa){
  int row = blockIdx.x;
  int seg = 0;
  #pragma unroll
  for (int s = 0; s < 8; ++s) if (row >= fa.rs[s+1]) seg = s + 1;
  int m = row - fa.rs[seg];
  const float* A = fa.d[seg].A + (size_t)m * 128;
  const float* B = fa.d[seg].B;
  int n = threadIdx.x;
  float acc = 0.f;
  for (int k = 0; k < 128; ++k) acc += A[k] * B[k*128 + n];
  fa.d[seg].C[(size_t)m*128 + n] = acc;
}

// b' = bd@wu_top + bs@wu_bot + bu
struct BiasArgs { const float* bd[4]; const float* bs[4]; const float* wu[4];
                  const float* bu[4]; float* outb[4]; };
__global__ void k_biasfold(BiasArgs ba){
  int s = blockIdx.x, j = threadIdx.x;
  const float* wu = ba.wu[s];
  float acc = ba.bu[s][j];
  for (int k = 0; k < 128; ++k)
    acc += ba.bd[s][k] * wu[k*128 + j] + ba.bs[s][k] * wu[(128 + k)*128 + j];
  ba.outb[s][j] = acc;
}

// ============================ main GEMM =================================
// C[M,128] = A[M,K] @ B[K,128] (+bias[128]) (+extra[M,128])
// block 256 threads, tile 128x128, K-chunk 32. fp32 outer-product 8x8/thread.
__global__ __launch_bounds__(256, 4)
void k_gemm(const float* __restrict__ A, const float* __restrict__ B,
            const float* __restrict__ bias, const float* __restrict__ extra,
            float* __restrict__ C, int M, int K)
{
  __shared__ __align__(16) float As[128][36];   // [m][k], stride 36 kills bank conflicts
  __shared__ __align__(16) float Bs[32][128];   // [k][n]
  const int tid = threadIdx.x;
  const int rowBase = blockIdx.x * 128;
  const int mi = tid >> 4, ni = tid & 15;

  float4 acc[2][4][2];
  #pragma unroll
  for (int r = 0; r < 2; ++r)
    #pragma unroll
    for (int i = 0; i < 4; ++i)
      #pragma unroll
      for (int c = 0; c < 2; ++c) acc[r][i][c] = make_float4(0.f,0.f,0.f,0.f);

  const int lk = tid & 7,  lm = tid >> 3;   // A staging: 8 float4 per row-chunk
  const int bn = tid & 31, bk = tid >> 5;   // B staging

  for (int k0 = 0; k0 < K; k0 += 32){
    #pragma unroll
    for (int p = 0; p < 4; ++p){
      int m = p*32 + lm;
      int gm = rowBase + m;
      float4 v = make_float4(0.f,0.f,0.f,0.f);
      if (gm < M) v = *(const float4*)(A + (size_t)gm*K + k0 + lk*4);
      *(float4*)&As[m][lk*4] = v;
    }
    #pragma unroll
    for (int p = 0; p < 4; ++p){
      int k = p*8 + bk;
      float4 v = *(const float4*)(B + (size_t)(k0 + k)*128 + bn*4);
      *(float4*)&Bs[k][bn*4] = v;
    }
    __syncthreads();
    #pragma unroll 4
    for (int k = 0; k < 32; ++k){
      float4 b0 = *(const float4*)&Bs[k][ni*4];
      float4 b1 = *(const float4*)&Bs[k][ni*4 + 64];
      #pragma unroll
      for (int r = 0; r < 2; ++r){
        #pragma unroll
        for (int i = 0; i < 4; ++i){
          float a = As[r*64 + mi*4 + i][k];
          fma4(acc[r][i][0], a, b0);
          fma4(acc[r][i][1], a, b1);
        }
      }
    }
    __syncthreads();
  }

  float4 bb0 = make_float4(0.f,0.f,0.f,0.f), bb1 = bb0;
  if (bias){ bb0 = *(const float4*)(bias + ni*4); bb1 = *(const float4*)(bias + ni*4 + 64); }
  #pragma unroll
  for (int r = 0; r < 2; ++r){
    #pragma unroll
    for (int i = 0; i < 4; ++i){
      int gm = rowBase + r*64 + mi*4 + i;
      if (gm >= M) continue;
      float4 v0 = acc[r][i][0], v1 = acc[r][i][1];
      add4(v0, bb0); add4(v1, bb1);
      if (extra){
        const float* erow = extra + (size_t)gm*128;
        add4(v0, *(const float4*)(erow + ni*4));
        add4(v1, *(const float4*)(erow + ni*4 + 64));
      }
      float* crow = C + (size_t)gm*128;
      *(float4*)(crow + ni*4)      = v0;
      *(float4*)(crow + ni*4 + 64) = v1;
    }
  }
}

// ============================ mean-aggregate ============================
// 2 dst nodes per 256-thread block; lanes = columns (coalesced 512B row reads)
__global__ void k_agg(const float* __restrict__ t, const int* __restrict__ off,
                      const int* __restrict__ deg, const int* __restrict__ col,
                      float* __restrict__ o){
  int d = blockIdx.x * 2 + (threadIdx.x >> 7);
  int c = threadIdx.x & 127;
  int s0 = off[d], cnt = deg[d];
  float acc = 0.f;
  for (int i = 0; i < cnt; ++i){
    int s = col[s0 + i];
    acc += t[(size_t)s*128 + c];
  }
  float inv = 1.0f / (float)(cnt > 0 ? cnt : 1);
  o[(size_t)d*128 + c] = acc * inv;
}

// ============================ batchnorm + lrelu =========================
__global__ void k_stats(const float* __restrict__ x, float* __restrict__ stats, int M){
  int c = threadIdx.x & 127, half = threadIdx.x >> 7;
  float s = 0.f, s2 = 0.f;
  for (int r = blockIdx.x*2 + half; r < M; r += gridDim.x*2){
    float v = x[(size_t)r*128 + c];
    s += v; s2 += v*v;
  }
  __shared__ float sh[256];
  sh[threadIdx.x] = s; __syncthreads();
  if (half == 0) atomicAdd(&stats[c], s + sh[threadIdx.x + 128]);
  __syncthreads();
  sh[threadIdx.x] = s2; __syncthreads();
  if (half == 0) atomicAdd(&stats[128 + c], s2 + sh[threadIdx.x + 128]);
}

__global__ void k_bnprep(const float* __restrict__ stats, const float* __restrict__ g,
                         const float* __restrict__ b, float* __restrict__ sc, int M){
  int c = threadIdx.x;
  float invN = 1.0f / (float)M;
  float m  = stats[c] * invN;
  float var = stats[128 + c] * invN - m*m;
  float scale = g[c] / sqrtf(var + 1.0f);
  sc[c] = scale;
  sc[128 + c] = b[c] - m*scale;
}

__global__ void k_bn(float* __restrict__ x, const float* __restrict__ sc, int M){
  int idx = blockIdx.x*256 + threadIdx.x;   // float4 index
  if (idx >= M*32) return;
  int c = (idx & 31) * 4;
  float4 v = ((float4*)x)[idx];
  float s0=sc[c],s1=sc[c+1],s2=sc[c+2],s3=sc[c+3];
  float h0=sc[128+c],h1=sc[129+c],h2=sc[130+c],h3=sc[131+c];
  v.x = v.x*s0 + h0; v.x = v.x >= 0.f ? v.x : 0.01f*v.x;
  v.y = v.y*s1 + h1; v.y = v.y >= 0.f ? v.y : 0.01f*v.y;
  v.z = v.z*s2 + h2; v.z = v.z >= 0.f ? v.z : 0.01f*v.z;
  v.w = v.w*s3 + h3; v.w = v.w >= 0.f ? v.w : 0.01f*v.w;
  ((float4*)x)[idx] = v;
}

// ============================ heads =====================================
template<int LC>
__global__ void k_head(const float* __restrict__ h, const float* __restrict__ w,
                       const float* __restrict__ b, float* __restrict__ o, int M){
  __shared__ float ws[128*LC];
  __shared__ float bs[LC];
  for (int i = threadIdx.x; i < 128*LC; i += 256) ws[i] = w[i];
  if (threadIdx.x < LC) bs[threadIdx.x] = b[threadIdx.x];
  __syncthreads();
  int r = blockIdx.x*256 + threadIdx.x;
  if (r >= M) return;
  float acc[LC];
  #pragma unroll
  for (int c = 0; c < LC; ++c) acc[c] = bs[c];
  const float4* hr = (const float4*)(h + (size_t)r*128);
  for (int k4 = 0; k4 < 32; ++k4){
    float4 v = hr[k4];
    int k = k4*4;
    #pragma unroll
    for (int c = 0; c < LC; ++c)
      acc[c] += v.x*ws[k*LC+c] + v.y*ws[(k+1)*LC+c] + v.z*ws[(k+2)*LC+c] + v.w*ws[(k+3)*LC+c];
  }
  #pragma unroll
  for (int c = 0; c < LC; ++c) o[(size_t)r*LC + c] = acc[c];
}

// ============================ launch ====================================
extern "C" void kernel_launch(void* const* d_in, const int* in_sizes, int n_in,
                              void* d_out, int out_size, void* d_ws, size_t ws_size,
                              hipStream_t stream) {
  const float* x_author = (const float*)d_in[0];   // [NN,256]
  const float* x_paper  = (const float*)d_in[1];   // [NN,128]
  const int*   ei_pa    = (const int*)d_in[2];     // [2,NE] row0 paper-src, row1 author-dst
  const int*   ei_ap    = (const int*)d_in[3];     // [2,NE] row0 author-src, row1 paper-dst

  // workspace carve (~212 MB total)
  char* p = (char*)d_ws;
  auto alloc = [&](size_t bytes) -> void* {
    void* r = (void*)p; p += (bytes + 255) & ~(size_t)255; return r;
  };
  float* w1a_d = (float*)alloc(256*128*4);  float* w1a_s = (float*)alloc(128*128*4);
  float* w1p_d = (float*)alloc(128*128*4);  float* w1p_s = (float*)alloc(256*128*4);
  float* w2a_d = (float*)alloc(128*128*4);  float* w2a_s = (float*)alloc(128*128*4);
  float* w2p_d = (float*)alloc(128*128*4);  float* w2p_s = (float*)alloc(128*128*4);
  float* w1a_b = (float*)alloc(128*4);      float* w1p_b = (float*)alloc(128*4);
  float* w2a_b = (float*)alloc(128*4);      float* w2p_b = (float*)alloc(128*4);
  float* stats = (float*)alloc(256*4);      float* bnsc  = (float*)alloc(256*4);
  int* deg2  = (int*)alloc(2*NN*4);
  int* off2  = (int*)alloc(2*NN*4);
  int* cur2  = (int*)alloc(2*NN*4);
  int* col_pa = (int*)alloc(NE*4);
  int* col_ap = (int*)alloc(NE*4);
  int* bsum  = (int*)alloc(1024*4);
  int* bsoff = (int*)alloc(1024*4);
  const size_t NB = (size_t)NN * 128;
  float* B1 = (float*)alloc(NB*4);  // h_author (layer1, activated)
  float* B2 = (float*)alloc(NB*4);  // h_paper
  float* B3 = (float*)alloc(NB*4);  // temp src-transform / h_a2
  float* B4 = (float*)alloc(NB*4);  // agg / temp / h_p2

  // ---- CSR build (shared by both layers) ----
  hipMemsetAsync(deg2, 0, 2*NN*4, stream);
  k_count<<<(2*NE + 255)/256, 256, 0, stream>>>(ei_pa, ei_ap, deg2);
  k_bsum <<<2*NBLK, 256, 0, stream>>>(deg2, bsum);
  k_bscan<<<2, 512, 0, stream>>>(bsum, bsoff);
  k_scanC<<<2*NBLK, 256, 0, stream>>>(deg2, bsoff, off2, cur2);
  k_fill <<<(2*NE + 255)/256, 256, 0, stream>>>(ei_pa, ei_ap, cur2, col_pa, col_ap);

  // ---- fold weights ----
  FoldArgs fa;
  const float* wu1a = (const float*)d_in[8];
  const float* wu1p = (const float*)d_in[14];
  const float* wu2a = (const float*)d_in[20];
  const float* wu2p = (const float*)d_in[26];
  fa.d[0] = { (const float*)d_in[6],  wu1a,           w1a_d };  // wd(256) @ wu_top
  fa.d[1] = { (const float*)d_in[4],  wu1a + 128*128, w1a_s };  // ws(128) @ wu_bot
  fa.d[2] = { (const float*)d_in[12], wu1p,           w1p_d };
  fa.d[3] = { (const float*)d_in[10], wu1p + 128*128, w1p_s };
  fa.d[4] = { (const float*)d_in[18], wu2a,           w2a_d };
  fa.d[5] = { (const float*)d_in[16], wu2a + 128*128, w2a_s };
  fa.d[6] = { (const float*)d_in[24], wu2p,           w2p_d };
  fa.d[7] = { (const float*)d_in[22], wu2p + 128*128, w2p_s };
  int rows[8] = {256,128,128,256,128,128,128,128};
  fa.rs[0] = 0;
  for (int i = 0; i < 8; ++i) fa.rs[i+1] = fa.rs[i] + rows[i];
  k_fold<<<fa.rs[8], 128, 0, stream>>>(fa);

  BiasArgs ba;
  ba.bd[0]=(const float*)d_in[7];  ba.bs[0]=(const float*)d_in[5];  ba.wu[0]=wu1a; ba.bu[0]=(const float*)d_in[9];  ba.outb[0]=w1a_b;
  ba.bd[1]=(const float*)d_in[13]; ba.bs[1]=(const float*)d_in[11]; ba.wu[1]=wu1p; ba.bu[1]=(const float*)d_in[15]; ba.outb[1]=w1p_b;
  ba.bd[2]=(const float*)d_in[19]; ba.bs[2]=(const float*)d_in[17]; ba.wu[2]=wu2a; ba.bu[2]=(const float*)d_in[21]; ba.outb[2]=w2a_b;
  ba.bd[3]=(const float*)d_in[25]; ba.bs[3]=(const float*)d_in[23]; ba.wu[3]=wu2p; ba.bu[3]=(const float*)d_in[27]; ba.outb[3]=w2p_b;
  k_biasfold<<<4, 128, 0, stream>>>(ba);

  const int GEMM_GRID = (NN + 127)/128;   // 782
  const int* off_pa = off2;        const int* deg_pa = deg2;
  const int* off_ap = off2 + NN;   const int* deg_ap = deg2 + NN;

  auto bn_block = [&](float* h, const float* g, const float* be){
    hipMemsetAsync(stats, 0, 256*4, stream);
    k_stats <<<256, 256, 0, stream>>>(h, stats, NN);
    k_bnprep<<<1, 128, 0, stream>>>(stats, g, be, bnsc, NN);
    k_bn    <<<NN*32/256, 256, 0, stream>>>(h, bnsc, NN);
  };

  // ---- layer 1, author (p2a) ----
  k_gemm<<<GEMM_GRID, 256, 0, stream>>>(x_paper, w1a_s, nullptr, nullptr, B3, NN, 128);
  k_agg <<<NN/2, 256, 0, stream>>>(B3, off_pa, deg_pa, col_pa, B4);
  k_gemm<<<GEMM_GRID, 256, 0, stream>>>(x_author, w1a_d, w1a_b, B4, B1, NN, 256);
  bn_block(B1, (const float*)d_in[28], (const float*)d_in[29]);

  // ---- layer 1, paper (a2p) ----
  k_gemm<<<GEMM_GRID, 256, 0, stream>>>(x_author, w1p_s, nullptr, nullptr, B3, NN, 256);
  k_agg <<<NN/2, 256, 0, stream>>>(B3, off_ap, deg_ap, col_ap, B4);
  k_gemm<<<GEMM_GRID, 256, 0, stream>>>(x_paper, w1p_d, w1p_b, B4, B2, NN, 128);
  bn_block(B2, (const float*)d_in[30], (const float*)d_in[31]);

  // ---- layer 2, author (p2a; src = B2, dst = B1) ----
  k_gemm<<<GEMM_GRID, 256, 0, stream>>>(B2, w2a_s, nullptr, nullptr, B3, NN, 128);
  k_agg <<<NN/2, 256, 0, stream>>>(B3, off_pa, deg_pa, col_pa, B4);
  k_gemm<<<GEMM_GRID, 256, 0, stream>>>(B1, w2a_d, w2a_b, B4, B3, NN, 128);  // h_a2 -> B3
  bn_block(B3, (const float*)d_in[32], (const float*)d_in[33]);
  k_head<4><<<(NN + 255)/256, 256, 0, stream>>>(B3, (const float*)d_in[36], (const float*)d_in[37],
                                                (float*)d_out, NN);

  // ---- layer 2, paper (a2p; src = B1, dst = B2) ----
  k_gemm<<<GEMM_GRID, 256, 0, stream>>>(B1, w2p_s, nullptr, nullptr, B4, NN, 128);
  k_agg <<<NN/2, 256, 0, stream>>>(B4, off_ap, deg_ap, col_ap, B1);          // agg -> B1 (free)
  k_gemm<<<GEMM_GRID, 256, 0, stream>>>(B2, w2p_d, w2p_b, B1, B4, NN, 128);  // h_p2 -> B4
  bn_block(B4, (const float*)d_in[34], (const float*)d_in[35]);
  k_head<7><<<(NN + 255)/256, 256, 0, stream>>>(B4, (const float*)d_in[38], (const float*)d_in[39],
                                                (float*)d_out + (size_t)NN*4, NN);
}